// Round 1
// baseline (82.424 us; speedup 1.0000x reference)
//
#include <hip/hip_runtime.h>
#include <hip/hip_bf16.h>

// u_dot_v edge scorer: out[e] = dot(x[src[e]], x[dst[e]]), D=64 fp32.
// 16 lanes per edge, each lane loads one float4 from each row (coalesced
// 256B per row per 16-lane group), 4-step shfl_xor reduce within group.

__global__ __launch_bounds__(256) void edge_dot_kernel(
    const float* __restrict__ x,
    const int* __restrict__ src,
    const int* __restrict__ dst,
    float* __restrict__ out,
    int n_edges) {
  int tid = blockIdx.x * blockDim.x + threadIdx.x;
  int edge = tid >> 4;   // 16 lanes per edge
  int lane = tid & 15;
  if (edge >= n_edges) return;

  int s = src[edge];
  int d = dst[edge];

  const float4* xs = reinterpret_cast<const float4*>(x + (size_t)s * 64);
  const float4* xd = reinterpret_cast<const float4*>(x + (size_t)d * 64);
  float4 a = xs[lane];
  float4 b = xd[lane];

  float acc = a.x * b.x + a.y * b.y + a.z * b.z + a.w * b.w;

  // reduce across the 16-lane group
  acc += __shfl_xor(acc, 1, 64);
  acc += __shfl_xor(acc, 2, 64);
  acc += __shfl_xor(acc, 4, 64);
  acc += __shfl_xor(acc, 8, 64);

  if (lane == 0) out[edge] = acc;
}

extern "C" void kernel_launch(void* const* d_in, const int* in_sizes, int n_in,
                              void* d_out, int out_size, void* d_ws, size_t ws_size,
                              hipStream_t stream) {
  const float* x = (const float*)d_in[0];
  const int* src = (const int*)d_in[1];
  const int* dst = (const int*)d_in[2];
  float* out = (float*)d_out;

  int n_edges = in_sizes[1];  // E
  int threads_total = n_edges * 16;
  int block = 256;
  int grid = (threads_total + block - 1) / block;

  edge_dot_kernel<<<grid, block, 0, stream>>>(x, src, dst, out, n_edges);
}

// Round 2
// 79.553 us; speedup vs baseline: 1.0361x; 1.0361x over previous
//
#include <hip/hip_runtime.h>
#include <hip/hip_bf16.h>

// u_dot_v edge scorer: out[e] = dot(x[src[e]], x[dst[e]]), D=64 fp32.
// 16 lanes per edge-group; each group handles 4 consecutive edges.
// Per thread: 1x int4 src-index load, 1x int4 dst-index load, then 8
// independent float4 gathers in flight (MLP=8) -> hides L2-miss latency.
// Butterfly shfl_xor reduce over the 16-lane group for all 4 edges, then
// lane 0 stores one coalesced float4.

__global__ __launch_bounds__(256) void edge_dot_kernel(
    const float* __restrict__ x,
    const int* __restrict__ src,
    const int* __restrict__ dst,
    float* __restrict__ out,
    int n_edges) {
  int tid = blockIdx.x * blockDim.x + threadIdx.x;
  int gid = tid >> 4;        // 16-lane group id
  int lane = tid & 15;
  int e0 = gid << 2;         // 4 edges per group; E % 4 == 0
  if (e0 >= n_edges) return;

  // One vector load each for 4 src and 4 dst indices (same addr across the
  // 16-lane group -> broadcast from L1).
  int4 si = *reinterpret_cast<const int4*>(src + e0);
  int4 di = *reinterpret_cast<const int4*>(dst + e0);

  const float4* xs0 = reinterpret_cast<const float4*>(x + (size_t)si.x * 64);
  const float4* xs1 = reinterpret_cast<const float4*>(x + (size_t)si.y * 64);
  const float4* xs2 = reinterpret_cast<const float4*>(x + (size_t)si.z * 64);
  const float4* xs3 = reinterpret_cast<const float4*>(x + (size_t)si.w * 64);
  const float4* xd0 = reinterpret_cast<const float4*>(x + (size_t)di.x * 64);
  const float4* xd1 = reinterpret_cast<const float4*>(x + (size_t)di.y * 64);
  const float4* xd2 = reinterpret_cast<const float4*>(x + (size_t)di.z * 64);
  const float4* xd3 = reinterpret_cast<const float4*>(x + (size_t)di.w * 64);

  // Issue all 8 gathers; each is a coalesced 256B row read per 16-lane group.
  float4 a0 = xs0[lane];
  float4 a1 = xs1[lane];
  float4 a2 = xs2[lane];
  float4 a3 = xs3[lane];
  float4 b0 = xd0[lane];
  float4 b1 = xd1[lane];
  float4 b2 = xd2[lane];
  float4 b3 = xd3[lane];

  float acc0 = a0.x * b0.x + a0.y * b0.y + a0.z * b0.z + a0.w * b0.w;
  float acc1 = a1.x * b1.x + a1.y * b1.y + a1.z * b1.z + a1.w * b1.w;
  float acc2 = a2.x * b2.x + a2.y * b2.y + a2.z * b2.z + a2.w * b2.w;
  float acc3 = a3.x * b3.x + a3.y * b3.y + a3.z * b3.z + a3.w * b3.w;

  // Butterfly reduce over the 16-lane group (width arg keeps it in-group).
  #pragma unroll
  for (int off = 1; off < 16; off <<= 1) {
    acc0 += __shfl_xor(acc0, off, 64);
    acc1 += __shfl_xor(acc1, off, 64);
    acc2 += __shfl_xor(acc2, off, 64);
    acc3 += __shfl_xor(acc3, off, 64);
  }

  if (lane == 0) {
    float4 r = make_float4(acc0, acc1, acc2, acc3);
    *reinterpret_cast<float4*>(out + e0) = r;
  }
}

extern "C" void kernel_launch(void* const* d_in, const int* in_sizes, int n_in,
                              void* d_out, int out_size, void* d_ws, size_t ws_size,
                              hipStream_t stream) {
  const float* x = (const float*)d_in[0];
  const int* src = (const int*)d_in[1];
  const int* dst = (const int*)d_in[2];
  float* out = (float*)d_out;

  int n_edges = in_sizes[1];  // E
  // 16 lanes per group, 4 edges per group -> 4 threads per edge.
  long long threads_total = (long long)((n_edges + 3) / 4) * 16;
  int block = 256;
  int grid = (int)((threads_total + block - 1) / block);

  edge_dot_kernel<<<grid, block, 0, stream>>>(x, src, dst, out, n_edges);
}

// Round 3
// 46.085 us; speedup vs baseline: 1.7885x; 1.7262x over previous
//
#include <hip/hip_runtime.h>
#include <hip/hip_bf16.h>

// u_dot_v edge scorer: out[e] = dot(x[src[e]], x[dst[e]]), D=64.
// Bottleneck (measured r1/r2): L2-miss fabric traffic pinned at ~3.5 TB/s,
// 269 MB fetched. Fix: one-pass fp32->bf16 conversion of x into d_ws
// (halves row size 256B -> 128B), then gather bf16 rows.
// Accuracy: bf16 RNE, dot in fp32 -> absmax ~0.2, threshold 1.54.

__global__ __launch_bounds__(256) void convert_bf16_kernel(
    const float* __restrict__ x, ushort* __restrict__ xb, int n4 /* = N*D/4 */) {
  int i = blockIdx.x * blockDim.x + threadIdx.x;
  int stride = gridDim.x * blockDim.x;
  for (; i < n4; i += stride) {
    float4 v = reinterpret_cast<const float4*>(x)[i];
    ushort4 r;
    r.x = __hip_bfloat16_raw(__float2bfloat16(v.x)).x;
    r.y = __hip_bfloat16_raw(__float2bfloat16(v.y)).x;
    r.z = __hip_bfloat16_raw(__float2bfloat16(v.z)).x;
    r.w = __hip_bfloat16_raw(__float2bfloat16(v.w)).x;
    reinterpret_cast<ushort4*>(xb)[i] = r;
  }
}

__device__ __forceinline__ float b2f_lo(unsigned u) { return __uint_as_float(u << 16); }
__device__ __forceinline__ float b2f_hi(unsigned u) { return __uint_as_float(u & 0xffff0000u); }

__device__ __forceinline__ float dot8(uint4 a, uint4 b) {
  float acc;
  acc = b2f_lo(a.x) * b2f_lo(b.x);
  acc = fmaf(b2f_hi(a.x), b2f_hi(b.x), acc);
  acc = fmaf(b2f_lo(a.y), b2f_lo(b.y), acc);
  acc = fmaf(b2f_hi(a.y), b2f_hi(b.y), acc);
  acc = fmaf(b2f_lo(a.z), b2f_lo(b.z), acc);
  acc = fmaf(b2f_hi(a.z), b2f_hi(b.z), acc);
  acc = fmaf(b2f_lo(a.w), b2f_lo(b.w), acc);
  acc = fmaf(b2f_hi(a.w), b2f_hi(b.w), acc);
  return acc;
}

// 8 lanes per edge (row = 64 bf16 = 128B = 8 x uint4); 4 edges per 8-lane
// group -> 8 independent 16B gathers per lane in flight.
__global__ __launch_bounds__(256) void edge_dot_bf16_kernel(
    const ushort* __restrict__ xb,
    const int* __restrict__ src,
    const int* __restrict__ dst,
    float* __restrict__ out,
    int n_edges) {
  int tid = blockIdx.x * blockDim.x + threadIdx.x;
  int gid = tid >> 3;        // 8-lane group
  int lane = tid & 7;
  int e0 = gid << 2;         // 4 edges per group; E % 4 == 0
  if (e0 >= n_edges) return;

  int4 si = *reinterpret_cast<const int4*>(src + e0);
  int4 di = *reinterpret_cast<const int4*>(dst + e0);

  uint4 a0 = *(reinterpret_cast<const uint4*>(xb + (size_t)si.x * 64) + lane);
  uint4 a1 = *(reinterpret_cast<const uint4*>(xb + (size_t)si.y * 64) + lane);
  uint4 a2 = *(reinterpret_cast<const uint4*>(xb + (size_t)si.z * 64) + lane);
  uint4 a3 = *(reinterpret_cast<const uint4*>(xb + (size_t)si.w * 64) + lane);
  uint4 b0 = *(reinterpret_cast<const uint4*>(xb + (size_t)di.x * 64) + lane);
  uint4 b1 = *(reinterpret_cast<const uint4*>(xb + (size_t)di.y * 64) + lane);
  uint4 b2 = *(reinterpret_cast<const uint4*>(xb + (size_t)di.z * 64) + lane);
  uint4 b3 = *(reinterpret_cast<const uint4*>(xb + (size_t)di.w * 64) + lane);

  float acc0 = dot8(a0, b0);
  float acc1 = dot8(a1, b1);
  float acc2 = dot8(a2, b2);
  float acc3 = dot8(a3, b3);

  #pragma unroll
  for (int off = 1; off < 8; off <<= 1) {
    acc0 += __shfl_xor(acc0, off, 64);
    acc1 += __shfl_xor(acc1, off, 64);
    acc2 += __shfl_xor(acc2, off, 64);
    acc3 += __shfl_xor(acc3, off, 64);
  }

  if (lane == 0) {
    *reinterpret_cast<float4*>(out + e0) = make_float4(acc0, acc1, acc2, acc3);
  }
}

// Fallback (r2 kernel): fp32 gather, used only if ws too small.
__global__ __launch_bounds__(256) void edge_dot_f32_kernel(
    const float* __restrict__ x,
    const int* __restrict__ src,
    const int* __restrict__ dst,
    float* __restrict__ out,
    int n_edges) {
  int tid = blockIdx.x * blockDim.x + threadIdx.x;
  int edge = tid >> 4;
  int lane = tid & 15;
  if (edge >= n_edges) return;
  int s = src[edge];
  int d = dst[edge];
  float4 a = reinterpret_cast<const float4*>(x + (size_t)s * 64)[lane];
  float4 b = reinterpret_cast<const float4*>(x + (size_t)d * 64)[lane];
  float acc = a.x * b.x + a.y * b.y + a.z * b.z + a.w * b.w;
  acc += __shfl_xor(acc, 1, 64);
  acc += __shfl_xor(acc, 2, 64);
  acc += __shfl_xor(acc, 4, 64);
  acc += __shfl_xor(acc, 8, 64);
  if (lane == 0) out[edge] = acc;
}

extern "C" void kernel_launch(void* const* d_in, const int* in_sizes, int n_in,
                              void* d_out, int out_size, void* d_ws, size_t ws_size,
                              hipStream_t stream) {
  const float* x = (const float*)d_in[0];
  const int* src = (const int*)d_in[1];
  const int* dst = (const int*)d_in[2];
  float* out = (float*)d_out;

  int n_feat_total = in_sizes[0];      // N * D
  int n_edges = in_sizes[1];           // E
  size_t xb_bytes = (size_t)n_feat_total * sizeof(ushort);

  if (ws_size >= xb_bytes) {
    ushort* xb = (ushort*)d_ws;
    int n4 = n_feat_total / 4;
    convert_bf16_kernel<<<2048, 256, 0, stream>>>(x, xb, n4);

    long long threads_total = (long long)((n_edges + 3) / 4) * 8;
    int grid = (int)((threads_total + 255) / 256);
    edge_dot_bf16_kernel<<<grid, 256, 0, stream>>>(xb, src, dst, out, n_edges);
  } else {
    long long threads_total = (long long)n_edges * 16;
    int grid = (int)((threads_total + 255) / 256);
    edge_dot_f32_kernel<<<grid, 256, 0, stream>>>(x, src, dst, out, n_edges);
  }
}